// Round 11
// baseline (1542.754 us; speedup 1.0000x reference)
//
#include <hip/hip_runtime.h>
#include <hip/hip_bf16.h>

typedef __bf16 bf16x8 __attribute__((ext_vector_type(8)));
typedef float f32x4 __attribute__((ext_vector_type(4)));
typedef unsigned int u32x4 __attribute__((ext_vector_type(4)));
typedef unsigned short u16;
typedef unsigned int u32;

// ---------- helpers ----------
__device__ __forceinline__ u16 f2bf(float f) {
  union { float f; unsigned int i; } c;
  c.f = f;
  unsigned int x = c.i;
  return (u16)((x + 0x7fffu + ((x >> 16) & 1u)) >> 16);  // RNE
}
__device__ __forceinline__ float sigm(float x) { return 1.f / (1.f + __expf(-x)); }
__device__ __forceinline__ float tanh_fast(float x) {
  float e2 = __expf(2.f * x);
  return 1.f - 2.f / (e2 + 1.f);
}

// ---------- fp32 -> bf16 (vectorized; for w_ih) ----------
__global__ void cvt_f32_bf16_v4(const float* __restrict__ in, u16* __restrict__ out, int n4) {
  int stride = gridDim.x * blockDim.x;
  for (int i = blockIdx.x * blockDim.x + threadIdx.x; i < n4; i += stride) {
    float4 v = reinterpret_cast<const float4*>(in)[i];
    union { u16 u[4]; uint2 d; } o;
    o.u[0] = f2bf(v.x); o.u[1] = f2bf(v.y); o.u[2] = f2bf(v.z); o.u[3] = f2bf(v.w);
    reinterpret_cast<uint2*>(out)[i] = o.d;
  }
}

// ---------- x: [N=64][T=512][d=512] f32 -> [T][N][d] bf16 ; init 4 group h rings ----------
// Per group: [2][16 rows][512 u32words] (u32 = 2 bf16 units, low-elem LSB = parity tag).
__global__ void cvt_x_transpose(const float* __restrict__ in, u16* __restrict__ out,
                                u32* __restrict__ hbuf_u) {
  int gid = blockIdx.x * blockDim.x + threadIdx.x;
  if (gid < 65536) hbuf_u[gid] = ((gid >> 13) & 1) ? 1u : 0u;
  if (gid >= 64 * 512 * 64) return;
  int k8 = gid & 63, t = (gid >> 6) & 511, n = gid >> 15;
  const float* src = in + ((size_t)(n * 512 + t) << 9) + (k8 << 3);
  float4 a = reinterpret_cast<const float4*>(src)[0];
  float4 b = reinterpret_cast<const float4*>(src)[1];
  union { u16 u[8]; uint4 d; } o;
  o.u[0] = f2bf(a.x); o.u[1] = f2bf(a.y); o.u[2] = f2bf(a.z); o.u[3] = f2bf(a.w);
  o.u[4] = f2bf(b.x); o.u[5] = f2bf(b.y); o.u[6] = f2bf(b.z); o.u[7] = f2bf(b.w);
  *reinterpret_cast<uint4*>(out + ((size_t)(t * 64 + n) << 9) + (k8 << 3)) = o.d;
}

// ---------- batch-partitioned LSTM: 4 independent groups of 16 batch rows ----------
// 256 blocks x 256 threads. Block: grp=blk&3 (rows 16grp..+15), sli=blk>>2 (units 16sli..+15).
// w_hh slice bf16 LDS-resident; w_ih fragment register-resident (loop-invariant).
// 4 waves K-split h-GEMM; gp transposed [gatecol][batchrow] (conflict-free);
// h emitted via LDS repack -> 16B coherent stores.
__global__ void __launch_bounds__(256, 1) lstm_seq(
    const u16* __restrict__ xb,     // [512][64][512] bf16
    const u16* __restrict__ wib,    // [4096][512] bf16
    const float* __restrict__ w_hh, // [4096][1024] f32
    u32* __restrict__ hbuf_u,       // [4 grp][2][16][512] u32
    float* __restrict__ hTf,        // [64][1024] f32
    const float* __restrict__ b_ih, const float* __restrict__ b_hh) {
  __shared__ u16 wh[64][1032];           // 132,096 B; row l = gate*16 + ul
  __shared__ float gp[4][64][17];        // 17,408 B  [wave][gatecol][batchrow]
  __shared__ __align__(16) u32 hstg[16][8];  // 512 B  packed h words

  int blk = blockIdx.x, t = threadIdx.x;
  int grp = blk & 3, sli = blk >> 2;
  int u0 = sli << 4;

  // stage w_hh slice from f32 (once)
  for (int idx = t; idx < 64 * 128; idx += 256) {
    int l = idx >> 7, c8 = idx & 127;
    int gr = ((l >> 4) << 10) + u0 + (l & 15);
    const float* src = w_hh + ((size_t)gr << 10) + c8 * 8;
    float4 a = reinterpret_cast<const float4*>(src)[0];
    float4 c = reinterpret_cast<const float4*>(src)[1];
    union { u16 us[8]; bf16x8 v; } o;
    o.us[0] = f2bf(a.x); o.us[1] = f2bf(a.y); o.us[2] = f2bf(a.z); o.us[3] = f2bf(a.w);
    o.us[4] = f2bf(c.x); o.us[5] = f2bf(c.y); o.us[6] = f2bf(c.z); o.us[7] = f2bf(c.w);
    *(bf16x8*)(&wh[l][c8 * 8]) = o.v;
  }

  int lane = t & 63, wv = t >> 6;
  int lr = lane & 15, hi = lane >> 4, lk8 = hi << 3;
  int prow = t >> 4, pul = t & 15;

  float bI = b_ih[u0 + pul]        + b_hh[u0 + pul];
  float bF = b_ih[1024 + u0 + pul] + b_hh[1024 + u0 + pul];
  float bG = b_ih[2048 + u0 + pul] + b_hh[2048 + u0 + pul];
  float bO = b_ih[3072 + u0 + pul] + b_hh[3072 + u0 + pul];
  float c_ = 0.f;

  // register-resident w_ih fragment: wave wv covers x K-quarter [128wv,128wv+128)
  bf16x8 wi_r[4][4];
  {
    const u16* wb_ = wib + ((size_t)(u0 + lr) << 9) + (wv << 7) + lk8;
#pragma unroll
    for (int nt = 0; nt < 4; ++nt)
#pragma unroll
      for (int ks = 0; ks < 4; ++ks)
        wi_r[nt][ks] = *(const bf16x8*)(wb_ + ((size_t)nt << 19) + ks * 32);
  }

  u32* hgrp = hbuf_u + (grp << 14);   // 2 bufs x 8192 words
  __syncthreads();                     // weights staged

  for (int s = 0; s < 512; ++s) {
    f32x4 acc[4] = {};   // 4 gate n-tiles

    // x-GEMM (wi in registers; only xb touches memory)
    {
      const u16* xb_ = xb + ((size_t)s << 15) + (size_t)(((grp << 4) + lr) << 9) + (wv << 7) + lk8;
#pragma unroll
      for (int ks = 0; ks < 4; ++ks) {
        bf16x8 a = *(const bf16x8*)(xb_ + ks * 32);
#pragma unroll
        for (int nt = 0; nt < 4; ++nt)
          acc[nt] = __builtin_amdgcn_mfma_f32_16x16x32_bf16(a, wi_r[nt][ks], acc[nt], 0, 0, 0);
      }
    }

    if (s > 0) {
      // poll-load h(s) K-quarter: lane (lr,hi) -> row lr, words 128wv+4hi+16ks+[0,4)
      const u32* hb4 = hgrp + ((s & 1) << 13) + (lr << 9) + (wv << 7) + (hi << 2);
      u32 par = (u32)((s >> 1) & 1);
      u32x4 ha[8];
      int tries = 0;
      while (true) {
#define LDH(OFF) asm volatile("global_load_dwordx4 %0, %1, off offset:" #OFF " sc0 sc1" \
                              : "=v"(ha[OFF / 64]) : "v"(hb4) : "memory");
        LDH(0) LDH(64) LDH(128) LDH(192) LDH(256) LDH(320) LDH(384) LDH(448)
#undef LDH
        asm volatile("s_waitcnt vmcnt(0)" ::: "memory");
        __builtin_amdgcn_sched_barrier(0);          // rule #18
        u32 ok;
        if (par) {
          u32 r = 0xFFFFFFFFu;
#pragma unroll
          for (int i2 = 0; i2 < 8; ++i2)
            r &= (ha[i2][0] & ha[i2][1]) & (ha[i2][2] & ha[i2][3]);
          ok = r & 1u;
        } else {
          u32 r = 0u;
#pragma unroll
          for (int i2 = 0; i2 < 8; ++i2)
            r |= (ha[i2][0] | ha[i2][1]) | (ha[i2][2] | ha[i2][3]);
          ok = (~r) & 1u;
        }
        if (__all((int)ok)) break;
        if (++tries > (1 << 20)) break;             // fail loud, never hang
        __builtin_amdgcn_s_sleep(1);
      }
      __builtin_amdgcn_sched_barrier(0);
      // h-GEMM over this wave's K-quarter
#pragma unroll
      for (int ks = 0; ks < 8; ++ks) {
        union { u32x4 uu; bf16x8 v; } af; af.uu = ha[ks];
#pragma unroll
        for (int nt = 0; nt < 4; ++nt) {
          bf16x8 bfr = *(const bf16x8*)(&wh[(nt << 4) + lr][(wv << 8) + ks * 32 + lk8]);
          acc[nt] = __builtin_amdgcn_mfma_f32_16x16x32_bf16(af.v, bfr, acc[nt], 0, 0, 0);
        }
      }
    }

    // per-wave K-partials -> LDS (transposed: [gatecol][batchrow], 2-way max = free)
#pragma unroll
    for (int nt = 0; nt < 4; ++nt)
#pragma unroll
      for (int q = 0; q < 4; ++q)
        gp[wv][(nt << 4) + lr][(hi << 2) + q] = acc[nt][q];
    __syncthreads();

    // pointwise: reduce 4 wave-partials, cell update
    float g0 = gp[0][pul][prow]      + gp[1][pul][prow]      + gp[2][pul][prow]      + gp[3][pul][prow]      + bI;
    float g1 = gp[0][16 + pul][prow] + gp[1][16 + pul][prow] + gp[2][16 + pul][prow] + gp[3][16 + pul][prow] + bF;
    float g2 = gp[0][32 + pul][prow] + gp[1][32 + pul][prow] + gp[2][32 + pul][prow] + gp[3][32 + pul][prow] + bG;
    float g3 = gp[0][48 + pul][prow] + gp[1][48 + pul][prow] + gp[2][48 + pul][prow] + gp[3][48 + pul][prow] + bO;
    float ii = sigm(g0), ff = sigm(g1), tg = tanh_fast(g2), oo = sigm(g3);
    float cn = ff * c_ + ii * tg;
    c_ = cn;
    float hv = oo * tanh_fast(cn);

    if (s == 511) {
      hTf[((size_t)((grp << 4) + prow) << 10) + u0 + pul] = hv;  // plain; kernel-end flush
    } else {
      // pack h pair + parity tag into LDS staging
      u32 hb = (u32)f2bf(hv);
      u32 pn = (u32)__shfl_xor((int)hb, 1, 64);     // partner unit (pul^1), same wave
      if (!(pul & 1)) {
        u32 par1 = (u32)(((s + 1) >> 1) & 1);
        hstg[prow][pul >> 1] = ((hb & ~1u) | par1) | (pn << 16);
      }
    }
    __syncthreads();

    // coalesced 16B coherent h stores (32 lanes, fire-and-forget; tags carry correctness)
    if (s < 511 && t < 32) {
      int row = t >> 1, part = t & 1;
      u32x4 v = *(const u32x4*)(&hstg[row][part << 2]);
      u32* dst = hgrp + (((s + 1) & 1) << 13) + (row << 9) + (sli << 3) + (part << 2);
      asm volatile("global_store_dwordx4 %0, %1, off sc0 sc1" :: "v"(dst), "v"(v) : "memory");
    }
  }
}

// ---------- FC head: block n computes out[n] ----------
__global__ void fc_head(const float* __restrict__ hTf, const float* __restrict__ fc_w,
                        const float* __restrict__ fc_b, float* __restrict__ out) {
  __shared__ float red[4];
  int n = blockIdx.x, t = threadIdx.x;
  float4 hv = *(const float4*)(hTf + (n << 10) + t * 4);
  float4 wv = *(const float4*)(fc_w + t * 4);
  float s = hv.x * wv.x + hv.y * wv.y + hv.z * wv.z + hv.w * wv.w;
#pragma unroll
  for (int o = 32; o; o >>= 1) s += __shfl_down(s, o, 64);
  if ((t & 63) == 0) red[t >> 6] = s;
  __syncthreads();
  if (t == 0) out[n] = sigm(red[0] + red[1] + red[2] + red[3] + fc_b[0]);
}

// ---------- launch ----------
extern "C" void kernel_launch(void* const* d_in, const int* in_sizes, int n_in,
                              void* d_out, int out_size, void* d_ws, size_t ws_size,
                              hipStream_t stream) {
  const float* x    = (const float*)d_in[0];
  const float* w_ih = (const float*)d_in[1];
  const float* w_hh = (const float*)d_in[2];
  const float* b_ih = (const float*)d_in[3];
  const float* b_hh = (const float*)d_in[4];
  const float* fc_w = (const float*)d_in[5];
  const float* fc_b = (const float*)d_in[6];
  float* out = (float*)d_out;

  char* ws = (char*)d_ws;
  u16*   xb     = (u16*)(ws);                  // 33,554,432 B
  u16*   wib    = (u16*)(ws + 33554432);       //  4,194,304 B
  u32*   hbuf_u = (u32*)(ws + 37748736);       //    262,144 B  [4][2][16][512] u32
  float* hTf    = (float*)(ws + 38010880);     //    262,144 B

  cvt_x_transpose<<<8192, 256, 0, stream>>>(x, xb, hbuf_u);
  cvt_f32_bf16_v4<<<512, 256, 0, stream>>>(w_ih, wib, 2097152 / 4);
  lstm_seq<<<256, 256, 0, stream>>>(xb, wib, w_hh, hbuf_u, hTf, b_ih, b_hh);
  fc_head<<<64, 256, 0, stream>>>(hTf, fc_w, fc_b, out);
}